// Round 1
// baseline (810.704 us; speedup 1.0000x reference)
//
#include <hip/hip_runtime.h>
#include <hip/hip_bf16.h>

typedef __attribute__((ext_vector_type(8))) short bf16x8;
typedef __attribute__((ext_vector_type(4))) float f32x4;

__device__ __forceinline__ void async16(const void* g, void* l) {
    __builtin_amdgcn_global_load_lds(
        (const __attribute__((address_space(1))) unsigned int*)g,
        (__attribute__((address_space(3))) unsigned int*)l, 16, 0, 0);
}

// ---------------------------------------------------------------------------
// pack_x: x5 (f32, [16][512][16][300]) -> X3 (bf16, [16][16][300][512]) channel-last
// grid (256 bh, 5 wt, 8 ct), block 256. LDS-transposed so both sides coalesce.
// ---------------------------------------------------------------------------
__global__ __launch_bounds__(256) void pack_x(const float* __restrict__ x5,
                                              __hip_bfloat16* __restrict__ X3) {
    __shared__ float tile[64][65];
    const int bh = blockIdx.x;
    const int b = bh >> 4, h = bh & 15;
    const int w0 = blockIdx.y * 64, c0 = blockIdx.z * 64;
    const int tw = threadIdx.x & 63;
    const int tc = threadIdx.x >> 6;      // 0..3
#pragma unroll
    for (int i = 0; i < 16; ++i) {
        const int c = tc + i * 4;
        const int w = w0 + tw;
        float v = 0.f;
        if (w < 300) v = x5[((size_t)(b * 512 + c0 + c) * 16 + h) * 300 + w];
        tile[c][tw] = v;
    }
    __syncthreads();
    const int cp = (threadIdx.x & 31) * 2;
    const int wl0 = threadIdx.x >> 5;      // 0..7
#pragma unroll
    for (int i = 0; i < 8; ++i) {
        const int wl = wl0 + i * 8;
        const int w = w0 + wl;
        if (w < 300) {
            __hip_bfloat162 p;
            p.x = __float2bfloat16(tile[cp][wl]);
            p.y = __float2bfloat16(tile[cp + 1][wl]);
            *(__hip_bfloat162*)&X3[(((size_t)(b * 16 + h) * 300 + w)) * 512 + c0 + cp] = p;
        }
    }
}

// ---------------------------------------------------------------------------
// pack_a: conv_w(512,512,7) + cc_w(10,512,7) -> A2 bf16 [640][3584], kk=kh*512+ci
// grid (640, 14), block 256
// ---------------------------------------------------------------------------
__global__ __launch_bounds__(256) void pack_a(const float* __restrict__ conv_w,
                                              const float* __restrict__ cc_w,
                                              __hip_bfloat16* __restrict__ A2) {
    const int co = blockIdx.x;
    const int kk = blockIdx.y * 256 + threadIdx.x;   // 0..3583
    const int kh = kk >> 9;
    const int ci = kk & 511;
    float v = 0.f;
    if (co < 512)      v = conv_w[((size_t)co * 512 + ci) * 7 + kh];
    else if (co < 522) v = cc_w[((size_t)(co - 512) * 512 + ci) * 7 + kh];
    A2[(size_t)co * 3584 + kk] = __float2bfloat16(v);
}

// ---------------------------------------------------------------------------
// conv_gemm: implicit-im2col MFMA GEMM.
// C[co][n] = sum_{kh,ci} A2[co][kh*512+ci] * X3[b][ho(n)+kh][w(n)][ci]
// grid (5 m-tiles [fast, L2 B-reuse], 24 n-tiles, 16 b), block 256 (4 waves)
// rows 0..511 -> feats bf16 (+bias, relu); 512..521 -> scores f32 (+bias)
// ---------------------------------------------------------------------------
__global__ __launch_bounds__(256) void conv_gemm(
    const __hip_bfloat16* __restrict__ A2, const __hip_bfloat16* __restrict__ X3,
    const float* __restrict__ conv_b, const float* __restrict__ cc_b,
    __hip_bfloat16* __restrict__ feats, float* __restrict__ scores) {
    __shared__ __hip_bfloat16 As[4096];   // [128 rows][32 k] 64B rows
    __shared__ __hip_bfloat16 Bs[4096];   // [128 n]  [32 k] 64B rows
    const int tid = threadIdx.x;
    const int wv = tid >> 6;
    const int lane = tid & 63;
    const int m0 = blockIdx.x * 128;
    const int nt = blockIdx.y;
    const int b = blockIdx.z;

    // staging: each thread owns 2 A-rows-segments and 2 B-rows-segments (16B each)
    const int row0 = wv * 16 + (lane >> 2);   // 0..63
    const int row1 = row0 + 64;
    const int kseg = lane & 3;

    const size_t gA0 = (size_t)(m0 + row0) * 7168 + (size_t)kseg * 16;  // bytes
    const size_t gA1 = (size_t)(m0 + row1) * 7168 + (size_t)kseg * 16;

    int n0 = nt * 128 + row0; if (n0 > 2999) n0 = 2999;
    int n1 = nt * 128 + row1; if (n1 > 2999) n1 = 2999;
    const size_t gB0 = ((size_t)((b * 16 + n0 / 300) * 300 + n0 % 300)) * 1024 + (size_t)kseg * 16;
    const size_t gB1 = ((size_t)((b * 16 + n1 / 300) * 300 + n1 % 300)) * 1024 + (size_t)kseg * 16;

    char* lA0 = (char*)As + wv * 1024 + lane * 16;
    char* lA1 = lA0 + 4096;
    char* lB0 = (char*)Bs + wv * 1024 + lane * 16;
    char* lB1 = lB0 + 4096;
    const char* A2b = (const char*)A2;
    const char* X3b = (const char*)X3;

    const int wm = (wv & 1) * 64;
    const int wn = (wv >> 1) * 64;
    const int fl = lane & 15;
    const int fq = (lane >> 4) * 16;   // quad byte offset
    int aoff[4], boff[4];
#pragma unroll
    for (int i = 0; i < 4; ++i) {
        aoff[i] = (wm + i * 16 + fl) * 64 + fq;
        boff[i] = (wn + i * 16 + fl) * 64 + fq;
    }

    f32x4 acc[4][4] = {};

    for (int kt = 0; kt < 112; ++kt) {
        const size_t aadd = (size_t)kt * 64;                                   // kt*32 elems
        const size_t badd = (size_t)(kt >> 4) * 307200 + (size_t)(kt & 15) * 64; // kh*300*512*2 + ci0*2
        __syncthreads();                       // prev iter's LDS reads done
        async16(A2b + gA0 + aadd, lA0);
        async16(A2b + gA1 + aadd, lA1);
        async16(X3b + gB0 + badd, lB0);
        async16(X3b + gB1 + badd, lB1);
        __syncthreads();                       // loads landed (vmcnt(0) drain)
        bf16x8 af[4], bfv[4];
#pragma unroll
        for (int i = 0; i < 4; ++i) af[i] = *(const bf16x8*)((const char*)As + aoff[i]);
#pragma unroll
        for (int i = 0; i < 4; ++i) bfv[i] = *(const bf16x8*)((const char*)Bs + boff[i]);
#pragma unroll
        for (int mi = 0; mi < 4; ++mi)
#pragma unroll
            for (int ni = 0; ni < 4; ++ni)
                acc[mi][ni] = __builtin_amdgcn_mfma_f32_16x16x32_bf16(af[mi], bfv[ni], acc[mi][ni], 0, 0, 0);
    }

    // epilogue: D row = quad*4 + reg (co), col = lane&15 (n)
    const int quad4 = (lane >> 4) * 4;
#pragma unroll
    for (int ni = 0; ni < 4; ++ni) {
        const int n = nt * 128 + wn + ni * 16 + fl;
        if (n >= 3000) continue;
#pragma unroll
        for (int mi = 0; mi < 4; ++mi) {
            const int cob = m0 + wm + mi * 16 + quad4;
            const f32x4 v = acc[mi][ni];
#pragma unroll
            for (int r = 0; r < 4; ++r) {
                const int co = cob + r;
                float val = v[r];
                if (co < 512) {
                    val = fmaxf(val + conv_b[co], 0.f);
                    feats[(size_t)(b * 512 + co) * 3000 + n] = __float2bfloat16(val);
                } else if (co < 522) {
                    scores[(size_t)(b * 10 + (co - 512)) * 3000 + n] = val + cc_b[co - 512];
                }
            }
        }
    }
}

// ---------------------------------------------------------------------------
// softmax over k=10 (in-place scores->assign) + asum via atomics. grid (16,12)
// ---------------------------------------------------------------------------
__global__ __launch_bounds__(256) void softmax_assign(float* __restrict__ scores,
                                                      float* __restrict__ asum) {
    const int b = blockIdx.x;
    const int hw = blockIdx.y * 256 + threadIdx.x;
    const bool valid = hw < 3000;
    float part[10];
    if (valid) {
        float s[10], mx = -1e30f;
#pragma unroll
        for (int k = 0; k < 10; ++k) { s[k] = scores[(size_t)(b * 10 + k) * 3000 + hw]; mx = fmaxf(mx, s[k]); }
        float sum = 0.f;
#pragma unroll
        for (int k = 0; k < 10; ++k) { part[k] = __expf(s[k] - mx); sum += part[k]; }
        const float inv = 1.f / sum;
#pragma unroll
        for (int k = 0; k < 10; ++k) {
            part[k] *= inv;
            scores[(size_t)(b * 10 + k) * 3000 + hw] = part[k];
        }
    } else {
#pragma unroll
        for (int k = 0; k < 10; ++k) part[k] = 0.f;
    }
    __shared__ float red[4][10];
    const int lane = threadIdx.x & 63, w = threadIdx.x >> 6;
#pragma unroll
    for (int k = 0; k < 10; ++k) {
        float v = part[k];
        for (int off = 32; off; off >>= 1) v += __shfl_xor(v, off, 64);
        if (lane == 0) red[w][k] = v;
    }
    __syncthreads();
    if (threadIdx.x < 10)
        atomicAdd(&asum[b * 10 + threadIdx.x],
                  red[0][threadIdx.x] + red[1][threadIdx.x] + red[2][threadIdx.x] + red[3][threadIdx.x]);
}

// ---------------------------------------------------------------------------
// agg[b][k][c] = sum_hw assign[b][k][hw] * feats[b][c][hw]. grid (512 c, 16 b)
// ---------------------------------------------------------------------------
__global__ __launch_bounds__(256) void agg_kernel(const __hip_bfloat16* __restrict__ feats,
                                                  const float* __restrict__ assign,
                                                  float* __restrict__ agg) {
    const int c = blockIdx.x, b = blockIdx.y;
    const __hip_bfloat16* fp = feats + (size_t)(b * 512 + c) * 3000;
    float acc[10];
#pragma unroll
    for (int k = 0; k < 10; ++k) acc[k] = 0.f;
    for (int p = threadIdx.x; p < 1500; p += 256) {
        const int hw = p * 2;
        const __hip_bfloat162 f2 = *(const __hip_bfloat162*)&fp[hw];
        const float f0 = __bfloat162float(f2.x), f1 = __bfloat162float(f2.y);
#pragma unroll
        for (int k = 0; k < 10; ++k) {
            const float2 a2 = *(const float2*)&assign[(size_t)(b * 10 + k) * 3000 + hw];
            acc[k] += a2.x * f0 + a2.y * f1;
        }
    }
    __shared__ float red[4][10];
    const int lane = threadIdx.x & 63, w = threadIdx.x >> 6;
#pragma unroll
    for (int k = 0; k < 10; ++k) {
        float v = acc[k];
        for (int off = 32; off; off >>= 1) v += __shfl_xor(v, off, 64);
        if (lane == 0) red[w][k] = v;
    }
    __syncthreads();
    if (threadIdx.x < 10)
        agg[(size_t)(b * 10 + threadIdx.x) * 512 + c] =
            red[0][threadIdx.x] + red[1][threadIdx.x] + red[2][threadIdx.x] + red[3][threadIdx.x];
}

// ---------------------------------------------------------------------------
// vlad: cluster_res = agg - asum*centroid, L2-normalize per (b,k<8). grid (8,16)
// ---------------------------------------------------------------------------
__global__ __launch_bounds__(256) void vlad_kernel(const float* __restrict__ agg,
                                                   const float* __restrict__ asum,
                                                   const float* __restrict__ centroids,
                                                   float* __restrict__ vlad) {
    const int k = blockIdx.x, b = blockIdx.y;
    const int t = threadIdx.x;
    const float av = asum[b * 10 + k];
    const float r0 = agg[(size_t)(b * 10 + k) * 512 + t]       - av * centroids[k * 512 + t];
    const float r1 = agg[(size_t)(b * 10 + k) * 512 + t + 256] - av * centroids[k * 512 + t + 256];
    float v = r0 * r0 + r1 * r1;
    __shared__ float red[4];
    __shared__ float sscale;
    const int lane = t & 63, w = t >> 6;
    for (int off = 32; off; off >>= 1) v += __shfl_xor(v, off, 64);
    if (lane == 0) red[w] = v;
    __syncthreads();
    if (t == 0) {
        const float nrm = sqrtf(red[0] + red[1] + red[2] + red[3]);
        sscale = 1.f / fmaxf(nrm, 1e-12f);
    }
    __syncthreads();
    const float sc = sscale;
    vlad[(size_t)b * 4096 + k * 512 + t] = r0 * sc;
    vlad[(size_t)b * 4096 + k * 512 + t + 256] = r1 * sc;
}

// ---------------------------------------------------------------------------
// fc: emb = relu(vlad @ fc_w.T + fc_b) -> out[0:8192]. grid (8,16), block 64
// ---------------------------------------------------------------------------
__global__ __launch_bounds__(64) void fc_kernel(const float* __restrict__ vlad,
                                                const float* __restrict__ fc_w,
                                                const float* __restrict__ fc_b,
                                                float* __restrict__ out) {
    const int co = blockIdx.x * 64 + threadIdx.x;
    const int b = blockIdx.y;
    const float4* v4 = (const float4*)(vlad + (size_t)b * 4096);
    const float4* w4 = (const float4*)(fc_w + (size_t)co * 4096);
    float acc = 0.f;
    for (int i = 0; i < 1024; ++i) {
        const float4 a = v4[i], w = w4[i];
        acc += a.x * w.x + a.y * w.y + a.z * w.z + a.w * w.w;
    }
    out[b * 512 + co] = fmaxf(acc + fc_b[co], 0.f);
}

// ---------------------------------------------------------------------------
// logit: out[8192 + b*5994 + o] = emb[b] . logit_w[o]. grid (24,16), block 256
// ---------------------------------------------------------------------------
__global__ __launch_bounds__(256) void logit_kernel(const float* __restrict__ emb,
                                                    const float* __restrict__ logit_w,
                                                    float* __restrict__ out) {
    __shared__ float se[512];
    const int b = blockIdx.y;
    se[threadIdx.x] = emb[b * 512 + threadIdx.x];
    se[threadIdx.x + 256] = emb[b * 512 + threadIdx.x + 256];
    __syncthreads();
    const int o = blockIdx.x * 256 + threadIdx.x;
    if (o < 5994) {
        const float4* w4 = (const float4*)(logit_w + (size_t)o * 512);
        float acc = 0.f;
        for (int i = 0; i < 128; ++i) {
            const float4 w = w4[i];
            acc += w.x * se[4 * i] + w.y * se[4 * i + 1] + w.z * se[4 * i + 2] + w.w * se[4 * i + 3];
        }
        out[8192 + b * 5994 + o] = acc;
    }
}

extern "C" void kernel_launch(void* const* d_in, const int* in_sizes, int n_in,
                              void* d_out, int out_size, void* d_ws, size_t ws_size,
                              hipStream_t stream) {
    (void)in_sizes; (void)n_in; (void)out_size; (void)ws_size;
    const float* x5       = (const float*)d_in[0];
    const float* conv_w   = (const float*)d_in[5];
    const float* conv_b   = (const float*)d_in[6];
    const float* cc_w     = (const float*)d_in[7];
    const float* cc_b     = (const float*)d_in[8];
    const float* centroids= (const float*)d_in[9];
    const float* fc_w     = (const float*)d_in[10];
    const float* fc_b     = (const float*)d_in[11];
    const float* logit_w  = (const float*)d_in[12];
    float* out = (float*)d_out;

    char* ws = (char*)d_ws;
    __hip_bfloat16* X3    = (__hip_bfloat16*)(ws);              // 78,643,200 B
    __hip_bfloat16* A2    = (__hip_bfloat16*)(ws + 78643200);   //  4,587,520 B
    __hip_bfloat16* feats = (__hip_bfloat16*)(ws + 83230720);   // 49,152,000 B
    float* scores         = (float*)(ws + 132382720);           //  1,920,000 B (in-place assign)
    float* asum           = (float*)(ws + 134302720);           //        640 B
    float* agg            = (float*)(ws + 134303360);           //    327,680 B
    float* vlad           = (float*)(ws + 134631040);           //    262,144 B -> total ~134.9 MB

    hipMemsetAsync(asum, 0, 640, stream);
    pack_x<<<dim3(256, 5, 8), 256, 0, stream>>>(x5, X3);
    pack_a<<<dim3(640, 14), 256, 0, stream>>>(conv_w, cc_w, A2);
    conv_gemm<<<dim3(5, 24, 16), 256, 0, stream>>>(A2, X3, conv_b, cc_b, feats, scores);
    softmax_assign<<<dim3(16, 12), 256, 0, stream>>>(scores, asum);
    agg_kernel<<<dim3(512, 16), 256, 0, stream>>>(feats, scores, agg);
    vlad_kernel<<<dim3(8, 16), 256, 0, stream>>>(agg, asum, centroids, vlad);
    fc_kernel<<<dim3(8, 16), 64, 0, stream>>>(vlad, fc_w, fc_b, out);
    logit_kernel<<<dim3(24, 16), 256, 0, stream>>>(out, logit_w, out);
}

// Round 2
// 766.551 us; speedup vs baseline: 1.0576x; 1.0576x over previous
//
#include <hip/hip_runtime.h>
#include <hip/hip_bf16.h>

typedef __attribute__((ext_vector_type(8))) short bf16x8;
typedef __attribute__((ext_vector_type(4))) float f32x4;

__device__ __forceinline__ void async16(const void* g, void* l) {
    __builtin_amdgcn_global_load_lds(
        (const __attribute__((address_space(1))) unsigned int*)g,
        (__attribute__((address_space(3))) unsigned int*)l, 16, 0, 0);
}

// ---------------------------------------------------------------------------
// pack_x: x5 (f32, [16][512][16][300]) -> X3 (bf16, [16][16][300][512]) channel-last
// grid (256 bh, 5 wt, 8 ct), block 256. float4 reads, 8B bf16x4 writes.
// ---------------------------------------------------------------------------
__global__ __launch_bounds__(256) void pack_x(const float* __restrict__ x5,
                                              __hip_bfloat16* __restrict__ X3) {
    __shared__ float tile[64][65];
    const int bh = blockIdx.x;
    const int b = bh >> 4, h = bh & 15;
    const int w0 = blockIdx.y * 64, c0 = blockIdx.z * 64;
    const int lw = (threadIdx.x & 15) * 4;   // w within tile
    const int lc = threadIdx.x >> 4;         // c within pass
#pragma unroll
    for (int i = 0; i < 4; ++i) {
        const int c = lc + i * 16;
        const int w = w0 + lw;
        const float* src = &x5[((size_t)(b * 512 + c0 + c) * 16 + h) * 300 + w];
        float4 v = {0.f, 0.f, 0.f, 0.f};
        if (w + 3 < 300) v = *(const float4*)src;
        else {
            if (w < 300)     v.x = src[0];
            if (w + 1 < 300) v.y = src[1];
            if (w + 2 < 300) v.z = src[2];
            if (w + 3 < 300) v.w = src[3];
        }
        *(float4*)&tile[c][lw] = v;
    }
    __syncthreads();
    const int sc = (threadIdx.x & 15) * 4;   // c within tile (4 per lane)
    const int sw0 = threadIdx.x >> 4;        // 0..15
#pragma unroll
    for (int i = 0; i < 4; ++i) {
        const int wl = sw0 + i * 16;
        const int w = w0 + wl;
        if (w < 300) {
            __hip_bfloat16 p[4];
            p[0] = __float2bfloat16(tile[sc + 0][wl]);
            p[1] = __float2bfloat16(tile[sc + 1][wl]);
            p[2] = __float2bfloat16(tile[sc + 2][wl]);
            p[3] = __float2bfloat16(tile[sc + 3][wl]);
            *(uint2*)&X3[(((size_t)(b * 16 + h) * 300 + w)) * 512 + c0 + sc] = *(uint2*)p;
        }
    }
}

// ---------------------------------------------------------------------------
// pack_a: conv_w(512,512,7) + cc_w(10,512,7) -> A2 bf16 [640][3584], kk=kh*512+ci
// ---------------------------------------------------------------------------
__global__ __launch_bounds__(256) void pack_a(const float* __restrict__ conv_w,
                                              const float* __restrict__ cc_w,
                                              __hip_bfloat16* __restrict__ A2) {
    const int co = blockIdx.x;
    const int kk = blockIdx.y * 256 + threadIdx.x;
    const int kh = kk >> 9;
    const int ci = kk & 511;
    float v = 0.f;
    if (co < 512)      v = conv_w[((size_t)co * 512 + ci) * 7 + kh];
    else if (co < 522) v = cc_w[((size_t)(co - 512) * 512 + ci) * 7 + kh];
    A2[(size_t)co * 3584 + kk] = __float2bfloat16(v);
}

// ---------------------------------------------------------------------------
// conv_gemm: implicit-im2col MFMA GEMM with XOR-swizzled LDS (bank-conflict-free).
// LDS slot (row, s) holds global k-segment (s ^ ((row>>1)&3)).
// ---------------------------------------------------------------------------
__global__ __launch_bounds__(256) void conv_gemm(
    const __hip_bfloat16* __restrict__ A2, const __hip_bfloat16* __restrict__ X3,
    const float* __restrict__ conv_b, const float* __restrict__ cc_b,
    __hip_bfloat16* __restrict__ feats, float* __restrict__ scores) {
    __shared__ __hip_bfloat16 As[4096];   // [128 rows][32 k] 64B rows
    __shared__ __hip_bfloat16 Bs[4096];
    const int tid = threadIdx.x;
    const int wv = tid >> 6;
    const int lane = tid & 63;
    const int m0 = blockIdx.x * 128;
    const int nt = blockIdx.y;
    const int b = blockIdx.z;

    const int row0 = wv * 16 + (lane >> 2);   // 0..63
    const int row1 = row0 + 64;
    // swizzled source segment: (row>>1)&3 == (lane>>3)&3 for both row0 and row1
    const int kseg = (lane & 3) ^ ((lane >> 3) & 3);

    const size_t gA0 = (size_t)(m0 + row0) * 7168 + (size_t)kseg * 16;  // bytes
    const size_t gA1 = (size_t)(m0 + row1) * 7168 + (size_t)kseg * 16;

    int n0 = nt * 128 + row0; if (n0 > 2999) n0 = 2999;
    int n1 = nt * 128 + row1; if (n1 > 2999) n1 = 2999;
    const size_t gB0 = ((size_t)((b * 16 + n0 / 300) * 300 + n0 % 300)) * 1024 + (size_t)kseg * 16;
    const size_t gB1 = ((size_t)((b * 16 + n1 / 300) * 300 + n1 % 300)) * 1024 + (size_t)kseg * 16;

    char* lA0 = (char*)As + wv * 1024 + lane * 16;
    char* lA1 = lA0 + 4096;
    char* lB0 = (char*)Bs + wv * 1024 + lane * 16;
    char* lB1 = lB0 + 4096;
    const char* A2b = (const char*)A2;
    const char* X3b = (const char*)X3;

    const int wm = (wv & 1) * 64;
    const int wn = (wv >> 1) * 64;
    const int fl = lane & 15;
    const int sq = lane >> 4;                      // needed k-segment
    int aoff[4], boff[4];
#pragma unroll
    for (int i = 0; i < 4; ++i) {
        const int swz = (sq ^ ((fl >> 1) & 3)) * 16;   // (row>>1)&3 == (fl>>1)&3
        aoff[i] = (wm + i * 16 + fl) * 64 + swz;
        boff[i] = (wn + i * 16 + fl) * 64 + swz;
    }

    f32x4 acc[4][4] = {};

    for (int kt = 0; kt < 112; ++kt) {
        const size_t aadd = (size_t)kt * 64;
        const size_t badd = (size_t)(kt >> 4) * 307200 + (size_t)(kt & 15) * 64;
        __syncthreads();
        async16(A2b + gA0 + aadd, lA0);
        async16(A2b + gA1 + aadd, lA1);
        async16(X3b + gB0 + badd, lB0);
        async16(X3b + gB1 + badd, lB1);
        __syncthreads();
        bf16x8 af[4], bfv[4];
#pragma unroll
        for (int i = 0; i < 4; ++i) af[i] = *(const bf16x8*)((const char*)As + aoff[i]);
#pragma unroll
        for (int i = 0; i < 4; ++i) bfv[i] = *(const bf16x8*)((const char*)Bs + boff[i]);
#pragma unroll
        for (int mi = 0; mi < 4; ++mi)
#pragma unroll
            for (int ni = 0; ni < 4; ++ni)
                acc[mi][ni] = __builtin_amdgcn_mfma_f32_16x16x32_bf16(af[mi], bfv[ni], acc[mi][ni], 0, 0, 0);
    }

    const int quad4 = (lane >> 4) * 4;
#pragma unroll
    for (int ni = 0; ni < 4; ++ni) {
        const int n = nt * 128 + wn + ni * 16 + fl;
        if (n >= 3000) continue;
#pragma unroll
        for (int mi = 0; mi < 4; ++mi) {
            const int cob = m0 + wm + mi * 16 + quad4;
            const f32x4 v = acc[mi][ni];
#pragma unroll
            for (int r = 0; r < 4; ++r) {
                const int co = cob + r;
                float val = v[r];
                if (co < 512) {
                    val = fmaxf(val + conv_b[co], 0.f);
                    feats[(size_t)(b * 512 + co) * 3000 + n] = __float2bfloat16(val);
                } else if (co < 522) {
                    scores[(size_t)(b * 10 + (co - 512)) * 3000 + n] = val + cc_b[co - 512];
                }
            }
        }
    }
}

// ---------------------------------------------------------------------------
// softmax over k=10 (in-place scores->assign) + asum via atomics. grid (16,12)
// ---------------------------------------------------------------------------
__global__ __launch_bounds__(256) void softmax_assign(float* __restrict__ scores,
                                                      float* __restrict__ asum) {
    const int b = blockIdx.x;
    const int hw = blockIdx.y * 256 + threadIdx.x;
    const bool valid = hw < 3000;
    float part[10];
    if (valid) {
        float s[10], mx = -1e30f;
#pragma unroll
        for (int k = 0; k < 10; ++k) { s[k] = scores[(size_t)(b * 10 + k) * 3000 + hw]; mx = fmaxf(mx, s[k]); }
        float sum = 0.f;
#pragma unroll
        for (int k = 0; k < 10; ++k) { part[k] = __expf(s[k] - mx); sum += part[k]; }
        const float inv = 1.f / sum;
#pragma unroll
        for (int k = 0; k < 10; ++k) {
            part[k] *= inv;
            scores[(size_t)(b * 10 + k) * 3000 + hw] = part[k];
        }
    } else {
#pragma unroll
        for (int k = 0; k < 10; ++k) part[k] = 0.f;
    }
    __shared__ float red[4][10];
    const int lane = threadIdx.x & 63, w = threadIdx.x >> 6;
#pragma unroll
    for (int k = 0; k < 10; ++k) {
        float v = part[k];
        for (int off = 32; off; off >>= 1) v += __shfl_xor(v, off, 64);
        if (lane == 0) red[w][k] = v;
    }
    __syncthreads();
    if (threadIdx.x < 10)
        atomicAdd(&asum[b * 10 + threadIdx.x],
                  red[0][threadIdx.x] + red[1][threadIdx.x] + red[2][threadIdx.x] + red[3][threadIdx.x]);
}

// ---------------------------------------------------------------------------
// agg[b][k][c] = sum_hw assign[b][k][hw] * feats[b][c][hw]. grid (512 c, 16 b)
// ---------------------------------------------------------------------------
__global__ __launch_bounds__(256) void agg_kernel(const __hip_bfloat16* __restrict__ feats,
                                                  const float* __restrict__ assign,
                                                  float* __restrict__ agg) {
    const int c = blockIdx.x, b = blockIdx.y;
    const __hip_bfloat16* fp = feats + (size_t)(b * 512 + c) * 3000;
    float acc[10];
#pragma unroll
    for (int k = 0; k < 10; ++k) acc[k] = 0.f;
    for (int p = threadIdx.x; p < 1500; p += 256) {
        const int hw = p * 2;
        const __hip_bfloat162 f2 = *(const __hip_bfloat162*)&fp[hw];
        const float f0 = __bfloat162float(f2.x), f1 = __bfloat162float(f2.y);
#pragma unroll
        for (int k = 0; k < 10; ++k) {
            const float2 a2 = *(const float2*)&assign[(size_t)(b * 10 + k) * 3000 + hw];
            acc[k] += a2.x * f0 + a2.y * f1;
        }
    }
    __shared__ float red[4][10];
    const int lane = threadIdx.x & 63, w = threadIdx.x >> 6;
#pragma unroll
    for (int k = 0; k < 10; ++k) {
        float v = acc[k];
        for (int off = 32; off; off >>= 1) v += __shfl_xor(v, off, 64);
        if (lane == 0) red[w][k] = v;
    }
    __syncthreads();
    if (threadIdx.x < 10)
        agg[(size_t)(b * 10 + threadIdx.x) * 512 + c] =
            red[0][threadIdx.x] + red[1][threadIdx.x] + red[2][threadIdx.x] + red[3][threadIdx.x];
}

// ---------------------------------------------------------------------------
// vlad: cluster_res = agg - asum*centroid, L2-normalize per (b,k<8). grid (8,16)
// ---------------------------------------------------------------------------
__global__ __launch_bounds__(256) void vlad_kernel(const float* __restrict__ agg,
                                                   const float* __restrict__ asum,
                                                   const float* __restrict__ centroids,
                                                   float* __restrict__ vlad) {
    const int k = blockIdx.x, b = blockIdx.y;
    const int t = threadIdx.x;
    const float av = asum[b * 10 + k];
    const float r0 = agg[(size_t)(b * 10 + k) * 512 + t]       - av * centroids[k * 512 + t];
    const float r1 = agg[(size_t)(b * 10 + k) * 512 + t + 256] - av * centroids[k * 512 + t + 256];
    float v = r0 * r0 + r1 * r1;
    __shared__ float red[4];
    __shared__ float sscale;
    const int lane = t & 63, w = t >> 6;
    for (int off = 32; off; off >>= 1) v += __shfl_xor(v, off, 64);
    if (lane == 0) red[w] = v;
    __syncthreads();
    if (t == 0) {
        const float nrm = sqrtf(red[0] + red[1] + red[2] + red[3]);
        sscale = 1.f / fmaxf(nrm, 1e-12f);
    }
    __syncthreads();
    const float sc = sscale;
    vlad[(size_t)b * 4096 + k * 512 + t] = r0 * sc;
    vlad[(size_t)b * 4096 + k * 512 + t + 256] = r1 * sc;
}

// ---------------------------------------------------------------------------
// fc: emb = relu(vlad @ fc_w.T + fc_b) -> out[0:8192]. grid (16,16), block 256.
// 32 co per block, 8-way K-split per co, width-8 shfl reduce.
// ---------------------------------------------------------------------------
__global__ __launch_bounds__(256) void fc_kernel(const float* __restrict__ vlad,
                                                 const float* __restrict__ fc_w,
                                                 const float* __restrict__ fc_b,
                                                 float* __restrict__ out) {
    const int b = blockIdx.y;
    const int col = threadIdx.x >> 3;   // 0..31
    const int ks = threadIdx.x & 7;
    const int co = blockIdx.x * 32 + col;
    const float4* v4 = (const float4*)(vlad + (size_t)b * 4096);
    const float4* w4 = (const float4*)(fc_w + (size_t)co * 4096);
    float acc = 0.f;
    for (int i = ks; i < 1024; i += 8) {
        const float4 a = v4[i], w = w4[i];
        acc += a.x * w.x + a.y * w.y + a.z * w.z + a.w * w.w;
    }
    acc += __shfl_down(acc, 4, 8);
    acc += __shfl_down(acc, 2, 8);
    acc += __shfl_down(acc, 1, 8);
    if (ks == 0) out[b * 512 + co] = fmaxf(acc + fc_b[co], 0.f);
}

// ---------------------------------------------------------------------------
// logit: out[8192 + b*5994 + o] = emb[b].logit_w[o]. grid (16 b, 24 o-tiles):
// b-fastest so consecutive blocks share the same 512KB weight tile (L2-hot).
// ---------------------------------------------------------------------------
__global__ __launch_bounds__(256) void logit_kernel(const float* __restrict__ emb,
                                                    const float* __restrict__ logit_w,
                                                    float* __restrict__ out) {
    __shared__ float se[512];
    const int b = blockIdx.x;
    se[threadIdx.x] = emb[b * 512 + threadIdx.x];
    se[threadIdx.x + 256] = emb[b * 512 + threadIdx.x + 256];
    __syncthreads();
    const int o = blockIdx.y * 256 + threadIdx.x;
    if (o < 5994) {
        const float4* w4 = (const float4*)(logit_w + (size_t)o * 512);
        float acc = 0.f;
        for (int i = 0; i < 128; ++i) {
            const float4 w = w4[i];
            acc += w.x * se[4 * i] + w.y * se[4 * i + 1] + w.z * se[4 * i + 2] + w.w * se[4 * i + 3];
        }
        out[8192 + b * 5994 + o] = acc;
    }
}

extern "C" void kernel_launch(void* const* d_in, const int* in_sizes, int n_in,
                              void* d_out, int out_size, void* d_ws, size_t ws_size,
                              hipStream_t stream) {
    (void)in_sizes; (void)n_in; (void)out_size; (void)ws_size;
    const float* x5       = (const float*)d_in[0];
    const float* conv_w   = (const float*)d_in[5];
    const float* conv_b   = (const float*)d_in[6];
    const float* cc_w     = (const float*)d_in[7];
    const float* cc_b     = (const float*)d_in[8];
    const float* centroids= (const float*)d_in[9];
    const float* fc_w     = (const float*)d_in[10];
    const float* fc_b     = (const float*)d_in[11];
    const float* logit_w  = (const float*)d_in[12];
    float* out = (float*)d_out;

    char* ws = (char*)d_ws;
    __hip_bfloat16* X3    = (__hip_bfloat16*)(ws);              // 78,643,200 B
    __hip_bfloat16* A2    = (__hip_bfloat16*)(ws + 78643200);   //  4,587,520 B
    __hip_bfloat16* feats = (__hip_bfloat16*)(ws + 83230720);   // 49,152,000 B
    float* scores         = (float*)(ws + 132382720);           //  1,920,000 B
    float* asum           = (float*)(ws + 134302720);           //        640 B
    float* agg            = (float*)(ws + 134303360);           //    327,680 B
    float* vlad           = (float*)(ws + 134631040);           //    262,144 B

    hipMemsetAsync(asum, 0, 640, stream);
    pack_x<<<dim3(256, 5, 8), 256, 0, stream>>>(x5, X3);
    pack_a<<<dim3(640, 14), 256, 0, stream>>>(conv_w, cc_w, A2);
    conv_gemm<<<dim3(5, 24, 16), 256, 0, stream>>>(A2, X3, conv_b, cc_b, feats, scores);
    softmax_assign<<<dim3(16, 12), 256, 0, stream>>>(scores, asum);
    agg_kernel<<<dim3(512, 16), 256, 0, stream>>>(feats, scores, agg);
    vlad_kernel<<<dim3(8, 16), 256, 0, stream>>>(agg, asum, centroids, vlad);
    fc_kernel<<<dim3(16, 16), 256, 0, stream>>>(vlad, fc_w, fc_b, out);
    logit_kernel<<<dim3(16, 24), 256, 0, stream>>>(out, logit_w, out);
}